// Round 1
// baseline (244.850 us; speedup 1.0000x reference)
//
#include <hip/hip_runtime.h>
#include <hip/hip_bf16.h>

// B=1, Q=K=2048, C_IN=256, H=8, CH=32.
// Memory-bound on pair_bias (134 MB, read exactly once). Pipeline:
//   K0: weight transpose+bf16   K1: Q/K/V/gate projections (MFMA)
//   K2: flash attention w/ bias (the hot kernel)   K3: gated out-proj GEMM
#define QN 2048
#define KN 2048
#define CIN 256
#define NH 8
#define CH 32
#define HC 256  // NH*CH

typedef __attribute__((ext_vector_type(8))) short short8;
typedef __attribute__((ext_vector_type(4))) float f32x4;

__device__ __forceinline__ unsigned short f2bf(float f) {
  __hip_bfloat16 h = __float2bfloat16(f);
  return __builtin_bit_cast(unsigned short, h);
}

__device__ __forceinline__ short8 ld8(const unsigned short* p) {
  return *reinterpret_cast<const short8*>(p);
}

// ---------------- K0: weight transpose + f32->bf16 ----------------
// wT[z][n][k] for z in {q,k,v,g,o}; src matrices are [k][n] row-major.
__global__ __launch_bounds__(256) void k0_wtrans(
    const float* __restrict__ wq, const float* __restrict__ wk,
    const float* __restrict__ wv, const float* __restrict__ wg,
    const float* __restrict__ wo, unsigned short* __restrict__ wT) {
  __shared__ float tile[32][33];
  const int z = blockIdx.z;
  const float* src = (z == 0) ? wq : (z == 1) ? wk : (z == 2) ? wv : (z == 3) ? wg : wo;
  unsigned short* dst = wT + (size_t)z * CIN * CIN;
  const int kb = blockIdx.x * 32, nb = blockIdx.y * 32;
  const int tc = threadIdx.x & 31, tr = threadIdx.x >> 5;
#pragma unroll
  for (int p = 0; p < 4; ++p) {
    int r = p * 8 + tr;
    tile[r][tc] = src[(size_t)(kb + r) * CIN + nb + tc];
  }
  __syncthreads();
#pragma unroll
  for (int p = 0; p < 4; ++p) {
    int n = p * 8 + tr;
    dst[(size_t)(nb + n) * CIN + kb + tc] = f2bf(tile[tc][n]);
  }
}

// ---------------- K1: projections ----------------
// z=0: qh[h][q][ch]  (scaled 1/sqrt(32))   z=1: kh[h][k][ch]
// z=2: vT[h][ch][k]                        z=3: gate[q][h*32+ch] = sigmoid(.+bg)
__global__ __launch_bounds__(256) void k1_proj(
    const float* __restrict__ qx, const float* __restrict__ kvx,
    const unsigned short* __restrict__ wT, const float* __restrict__ bg,
    unsigned short* __restrict__ qh, unsigned short* __restrict__ kh,
    unsigned short* __restrict__ vT, float* __restrict__ gate) {
  const int z = blockIdx.z;
  const float* __restrict__ X = (z == 0 || z == 3) ? qx : kvx;
  const unsigned short* __restrict__ W = wT + (size_t)z * CIN * CIN;
  const int tid = threadIdx.x;
  const int w = tid >> 6, l = tid & 63, l15 = l & 15, g = l >> 4;
  const int row0 = blockIdx.x * 64 + (w >> 1) * 32;
  const int col0 = blockIdx.y * 64 + (w & 1) * 32;
  f32x4 acc[2][2] = {};
  for (int kk = 0; kk < CIN; kk += 32) {
    short8 a[2], b[2];
#pragma unroll
    for (int fi = 0; fi < 2; ++fi) {
      const float* ap = X + (size_t)(row0 + fi * 16 + l15) * CIN + kk + g * 8;
      const float4 lo = *reinterpret_cast<const float4*>(ap);
      const float4 hi = *reinterpret_cast<const float4*>(ap + 4);
      short8 v;
      v[0] = (short)f2bf(lo.x); v[1] = (short)f2bf(lo.y);
      v[2] = (short)f2bf(lo.z); v[3] = (short)f2bf(lo.w);
      v[4] = (short)f2bf(hi.x); v[5] = (short)f2bf(hi.y);
      v[6] = (short)f2bf(hi.z); v[7] = (short)f2bf(hi.w);
      a[fi] = v;
    }
#pragma unroll
    for (int fj = 0; fj < 2; ++fj)
      b[fj] = ld8(W + (size_t)(col0 + fj * 16 + l15) * CIN + kk + g * 8);
#pragma unroll
    for (int fi = 0; fi < 2; ++fi)
#pragma unroll
      for (int fj = 0; fj < 2; ++fj)
        acc[fi][fj] = __builtin_amdgcn_mfma_f32_16x16x32_bf16(a[fi], b[fj], acc[fi][fj], 0, 0, 0);
  }
#pragma unroll
  for (int fi = 0; fi < 2; ++fi)
#pragma unroll
    for (int fj = 0; fj < 2; ++fj)
#pragma unroll
      for (int r = 0; r < 4; ++r) {
        const int row = row0 + fi * 16 + g * 4 + r;
        const int col = col0 + fj * 16 + l15;
        const float v = acc[fi][fj][r];
        if (z == 0) {
          qh[((size_t)(col >> 5) * QN + row) * CH + (col & 31)] = f2bf(v * 0.17677669529663687f);
        } else if (z == 1) {
          kh[((size_t)(col >> 5) * KN + row) * CH + (col & 31)] = f2bf(v);
        } else if (z == 2) {
          vT[((size_t)(col >> 5) * CH + (col & 31)) * KN + row] = f2bf(v);
        } else {
          gate[(size_t)row * HC + col] = 1.f / (1.f + __expf(-(v + bg[col])));
        }
      }
}

// ---------------- K2: flash attention with pair bias ----------------
// Block = (q-strip of 16 rows, head). 4 waves each own a 512-wide K chunk,
// merge partials (online-softmax combine) via LDS at the end.
// Per 64-k tile: 4 QK^T mfma (bias enters through the C operand), wave-level
// softmax (shfl_xor over the 16-lane group), P transposed through per-wave
// LDS scratch (no barriers in the K loop), 4 PV mfma. Bias prefetched 1 tile.
__global__ __launch_bounds__(256, 4) void k2_attn(
    const unsigned short* __restrict__ qh, const unsigned short* __restrict__ kh,
    const unsigned short* __restrict__ vT, const float* __restrict__ pb_all,
    const float* __restrict__ mb, const float* __restrict__ gate,
    unsigned short* __restrict__ og) {
  __shared__ __align__(16) unsigned short p_lds[4][16][72];  // pad 8: conflict-min b128 reads
  __shared__ float o_lds[4][16][33];
  __shared__ float ml_lds[4][2][16];
  const int h = blockIdx.y;
  const int qb = blockIdx.x * 16;
  const int tid = threadIdx.x;
  const int w = tid >> 6, l = tid & 63, l15 = l & 15, g = l >> 4;
  const unsigned short* __restrict__ qp = qh + ((size_t)h * QN + qb) * CH;
  const unsigned short* __restrict__ kp = kh + (size_t)h * KN * CH;
  const unsigned short* __restrict__ vp = vT + (size_t)h * CH * KN;
  const int k0 = w * (KN / 4);
  const float* __restrict__ pbl = pb_all + ((size_t)h * QN + qb) * KN + k0 + l15;
  const float* pr0 = pbl + (size_t)(g * 4 + 0) * KN;
  const float* pr1 = pbl + (size_t)(g * 4 + 1) * KN;
  const float* pr2 = pbl + (size_t)(g * 4 + 2) * KN;
  const float* pr3 = pbl + (size_t)(g * 4 + 3) * KN;

  const short8 a_q = ld8(qp + l15 * CH + g * 8);
  f32x4 o0 = {}, o1 = {};
  float m[4] = {-3e38f, -3e38f, -3e38f, -3e38f};
  float ls[4] = {0.f, 0.f, 0.f, 0.f};
  float bc[4][4], bn[4][4];
#pragma unroll
  for (int kb = 0; kb < 4; ++kb) {
    bc[kb][0] = pr0[kb * 16];
    bc[kb][1] = pr1[kb * 16];
    bc[kb][2] = pr2[kb * 16];
    bc[kb][3] = pr3[kb * 16];
  }
  for (int t = 0; t < 8; ++t) {
    const int kt = k0 + t * 64;
    if (t < 7) {
      const int o = (t + 1) * 64;
#pragma unroll
      for (int kb = 0; kb < 4; ++kb) {
        bn[kb][0] = pr0[o + kb * 16];
        bn[kb][1] = pr1[o + kb * 16];
        bn[kb][2] = pr2[o + kb * 16];
        bn[kb][3] = pr3[o + kb * 16];
      }
    }
    float mbv[4];
#pragma unroll
    for (int kb = 0; kb < 4; ++kb) mbv[kb] = mb[kt + kb * 16 + l15];
    f32x4 s[4];
#pragma unroll
    for (int kb = 0; kb < 4; ++kb) {
      const short8 bk = ld8(kp + (size_t)(kt + kb * 16 + l15) * CH + g * 8);
      f32x4 cb;
#pragma unroll
      for (int r = 0; r < 4; ++r) cb[r] = bc[kb][r] + mbv[kb];
      s[kb] = __builtin_amdgcn_mfma_f32_16x16x32_bf16(a_q, bk, cb, 0, 0, 0);
    }
    // online softmax: rows live on (g*4+r); reduce over k across the 16-lane group
#pragma unroll
    for (int r = 0; r < 4; ++r) {
      float v = fmaxf(fmaxf(s[0][r], s[1][r]), fmaxf(s[2][r], s[3][r]));
      v = fmaxf(v, __shfl_xor(v, 1));
      v = fmaxf(v, __shfl_xor(v, 2));
      v = fmaxf(v, __shfl_xor(v, 4));
      v = fmaxf(v, __shfl_xor(v, 8));
      const float mn = fmaxf(m[r], v);
      const float sc = __expf(m[r] - mn);
      m[r] = mn;
      ls[r] *= sc;
      o0[r] *= sc;
      o1[r] *= sc;
    }
    float rs[4] = {0.f, 0.f, 0.f, 0.f};
#pragma unroll
    for (int kb = 0; kb < 4; ++kb)
#pragma unroll
      for (int r = 0; r < 4; ++r) {
        const float p = __expf(s[kb][r] - m[r]);
        s[kb][r] = p;
        rs[r] += p;
      }
#pragma unroll
    for (int r = 0; r < 4; ++r) {
      float v = rs[r];
      v += __shfl_xor(v, 1);
      v += __shfl_xor(v, 2);
      v += __shfl_xor(v, 4);
      v += __shfl_xor(v, 8);
      ls[r] += v;
    }
    // P -> per-wave LDS (C/D layout), read back as A fragments (same-wave, no barrier)
#pragma unroll
    for (int kb = 0; kb < 4; ++kb)
#pragma unroll
      for (int r = 0; r < 4; ++r)
        p_lds[w][g * 4 + r][kb * 16 + l15] = f2bf(s[kb][r]);
    const short8 ap0 = ld8(&p_lds[w][l15][g * 8]);
    const short8 ap1 = ld8(&p_lds[w][l15][32 + g * 8]);
    const unsigned short* vrow0 = vp + (size_t)l15 * KN + kt;
    const unsigned short* vrow1 = vp + (size_t)(16 + l15) * KN + kt;
    const short8 bv00 = ld8(vrow0 + g * 8);
    const short8 bv01 = ld8(vrow0 + 32 + g * 8);
    const short8 bv10 = ld8(vrow1 + g * 8);
    const short8 bv11 = ld8(vrow1 + 32 + g * 8);
    o0 = __builtin_amdgcn_mfma_f32_16x16x32_bf16(ap0, bv00, o0, 0, 0, 0);
    o0 = __builtin_amdgcn_mfma_f32_16x16x32_bf16(ap1, bv01, o0, 0, 0, 0);
    o1 = __builtin_amdgcn_mfma_f32_16x16x32_bf16(ap0, bv10, o1, 0, 0, 0);
    o1 = __builtin_amdgcn_mfma_f32_16x16x32_bf16(ap1, bv11, o1, 0, 0, 0);
    if (t < 7) {
#pragma unroll
      for (int kb = 0; kb < 4; ++kb)
#pragma unroll
        for (int r = 0; r < 4; ++r) bc[kb][r] = bn[kb][r];
    }
  }
  // publish per-chunk partials
#pragma unroll
  for (int r = 0; r < 4; ++r) {
    o_lds[w][g * 4 + r][l15] = o0[r];
    o_lds[w][g * 4 + r][16 + l15] = o1[r];
  }
#pragma unroll
  for (int r = 0; r < 4; ++r) {
    if (l15 == r) {
      ml_lds[w][0][g * 4 + r] = m[r];
      ml_lds[w][1][g * 4 + r] = ls[r];
    }
  }
  __syncthreads();
  // combine 4 chunks, apply gate, emit bf16 [q][h*32+ch]
#pragma unroll
  for (int it = 0; it < 2; ++it) {
    const int e = tid + it * 256;
    const int ql = e >> 5, ch = e & 31;
    const float m01 = fmaxf(ml_lds[0][0][ql], ml_lds[1][0][ql]);
    const float m23 = fmaxf(ml_lds[2][0][ql], ml_lds[3][0][ql]);
    const float mm = fmaxf(m01, m23);
    float L = 0.f, acc = 0.f;
#pragma unroll
    for (int c = 0; c < 4; ++c) {
      const float sc = __expf(ml_lds[c][0][ql] - mm);
      L += ml_lds[c][1][ql] * sc;
      acc += o_lds[c][ql][ch] * sc;
    }
    const size_t idx = (size_t)(qb + ql) * HC + h * CH + ch;
    og[idx] = f2bf((acc / L) * gate[idx]);
  }
}

// ---------------- K3: output projection + bias ----------------
__global__ __launch_bounds__(256) void k3_oproj(
    const unsigned short* __restrict__ og, const unsigned short* __restrict__ wToT,
    const float* __restrict__ bo, float* __restrict__ out) {
  const int tid = threadIdx.x;
  const int w = tid >> 6, l = tid & 63, l15 = l & 15, g = l >> 4;
  const int row0 = blockIdx.x * 64 + (w >> 1) * 32;
  const int col0 = blockIdx.y * 64 + (w & 1) * 32;
  f32x4 acc[2][2] = {};
  for (int kk = 0; kk < HC; kk += 32) {
    short8 a[2], b[2];
#pragma unroll
    for (int fi = 0; fi < 2; ++fi)
      a[fi] = ld8(og + (size_t)(row0 + fi * 16 + l15) * HC + kk + g * 8);
#pragma unroll
    for (int fj = 0; fj < 2; ++fj)
      b[fj] = ld8(wToT + (size_t)(col0 + fj * 16 + l15) * HC + kk + g * 8);
#pragma unroll
    for (int fi = 0; fi < 2; ++fi)
#pragma unroll
      for (int fj = 0; fj < 2; ++fj)
        acc[fi][fj] = __builtin_amdgcn_mfma_f32_16x16x32_bf16(a[fi], b[fj], acc[fi][fj], 0, 0, 0);
  }
#pragma unroll
  for (int fi = 0; fi < 2; ++fi)
#pragma unroll
    for (int fj = 0; fj < 2; ++fj)
#pragma unroll
      for (int r = 0; r < 4; ++r) {
        const int row = row0 + fi * 16 + g * 4 + r;
        const int col = col0 + fj * 16 + l15;
        out[(size_t)row * CIN + col] = acc[fi][fj][r] + bo[col];
      }
}

extern "C" void kernel_launch(void* const* d_in, const int* in_sizes, int n_in,
                              void* d_out, int out_size, void* d_ws, size_t ws_size,
                              hipStream_t stream) {
  const float* qx = (const float*)d_in[0];
  const float* kvx = (const float*)d_in[1];
  const float* pb = (const float*)d_in[2];
  const float* mbias = (const float*)d_in[3];
  const float* wq = (const float*)d_in[4];
  const float* wk = (const float*)d_in[5];
  const float* wv = (const float*)d_in[6];
  const float* wg = (const float*)d_in[7];
  const float* bg = (const float*)d_in[8];
  const float* wo = (const float*)d_in[9];
  const float* bo = (const float*)d_in[10];
  char* ws = (char*)d_ws;
  // workspace layout (bytes): wT 655360 | qh 1M | kh 1M | vT 1M | og 1M | gate 2M
  unsigned short* wT = (unsigned short*)(ws);
  unsigned short* qh = (unsigned short*)(ws + 655360);
  unsigned short* kh = (unsigned short*)(ws + 655360 + (1u << 20));
  unsigned short* vT = (unsigned short*)(ws + 655360 + 2u * (1u << 20));
  unsigned short* og = (unsigned short*)(ws + 655360 + 3u * (1u << 20));
  float* gate = (float*)(ws + 655360 + 4u * (1u << 20));
  float* out = (float*)d_out;

  k0_wtrans<<<dim3(8, 8, 5), 256, 0, stream>>>(wq, wk, wv, wg, wo, wT);
  k1_proj<<<dim3(32, 4, 4), 256, 0, stream>>>(qx, kvx, wT, bg, qh, kh, vT, gate);
  k2_attn<<<dim3(128, 8), 256, 0, stream>>>(qh, kh, vT, pb, mbias, gate, og);
  k3_oproj<<<dim3(32, 4), 256, 0, stream>>>(og, wT + 4 * 256 * 256, bo, out);
}